// Round 1
// baseline (375.992 us; speedup 1.0000x reference)
//
#include <hip/hip_runtime.h>
#include <hip/hip_bf16.h>

// Sizes (fixed by the problem; N/E/G derived from in_sizes at launch)
#define HID 256
#define ADDF 7
#define MLP1 128
#define BN_EPS 1e-5f
#define INV_SQRT2 0.70710678118654752f

__device__ __forceinline__ float gelu_exact(float z) {
    return 0.5f * z * (1.0f + erff(z * INV_SQRT2));
}

// ---------------- zero workspace ----------------
__global__ void k_zero(float* p, int n) {
    for (int i = blockIdx.x * blockDim.x + threadIdx.x; i < n; i += gridDim.x * blockDim.x)
        p[i] = 0.0f;
}

// ---------------- degree: deg[dst] += 1 per edge ----------------
__global__ void k_deg(const int* __restrict__ dst, float* __restrict__ deg, int E) {
    int i = blockIdx.x * blockDim.x + threadIdx.x;
    if (i < E) atomicAdd(&deg[dst[i]], 1.0f);
}

// ---------------- dinv[i] = rsqrt(deg[i] + 1 /*self loop*/) ----------------
__global__ void k_dinv(float* __restrict__ deg, int N) {
    int i = blockIdx.x * blockDim.x + threadIdx.x;
    if (i < N) {
        float d = deg[i] + 1.0f;   // self-loop; always >= 1
        deg[i] = rsqrtf(d);        // in-place -> dinv
    }
}

// ---------------- agg[dst] += x[src] * dinv[src] ----------------
__global__ void k_scatter(const int* __restrict__ src, const int* __restrict__ dst,
                          const float* __restrict__ x, const float* __restrict__ dinv,
                          float* __restrict__ agg, int E) {
    int i = blockIdx.x * blockDim.x + threadIdx.x;
    if (i < E) {
        int s = src[i];
        atomicAdd(&agg[dst[i]], x[s] * dinv[s]);
    }
}

// ---------------- s[i] = dinv[i]*(agg[i] + x[i]*dinv[i]);  cnt[batch[i]]++ ----------------
__global__ void k_node(const float* __restrict__ x, const float* __restrict__ dinv,
                       const float* __restrict__ agg, const int* __restrict__ batch,
                       float* __restrict__ s, int* __restrict__ cnt, int N) {
    int i = blockIdx.x * blockDim.x + threadIdx.x;
    if (i < N) {
        float di = dinv[i];
        s[i] = di * (agg[i] + x[i] * di);
        atomicAdd(&cnt[batch[i]], 1);
    }
}

// ---------------- heavy: h = gelu(s*a_j + b_j); accumulate S[g][j], T[j], T2[j] ----------------
#define CHUNK 128
__global__ __launch_bounds__(HID) void k_gelu_acc(
        const float* __restrict__ s, const int* __restrict__ batch,
        const float* __restrict__ Wc, const float* __restrict__ bc,
        float* __restrict__ Sgj, float* __restrict__ T, float* __restrict__ T2, int N) {
    __shared__ float sh_s[CHUNK];
    __shared__ int   sh_b[CHUNK];
    const int j = threadIdx.x;               // feature 0..255
    const int base = blockIdx.x * CHUNK;
    const int count = min(CHUNK, N - base);

    if (j < count) {
        sh_s[j] = s[base + j];
        sh_b[j] = batch[base + j];
    }
    __syncthreads();

    const float a = Wc[j];
    const float b = bc[j];
    float tsum = 0.f, t2sum = 0.f, gsum = 0.f;
    int gid = sh_b[0];

    for (int n = 0; n < count; ++n) {
        float z = fmaf(sh_s[n], a, b);
        float h = gelu_exact(z);
        tsum  += h;
        t2sum += h * h;
        int bg = sh_b[n];
        if (bg != gid) {                      // batch is sorted -> rare flush
            atomicAdd(&Sgj[gid * HID + j], gsum);
            gsum = 0.f;
            gid = bg;
        }
        gsum += h;
    }
    atomicAdd(&Sgj[gid * HID + j], gsum);
    atomicAdd(&T[j],  tsum);
    atomicAdd(&T2[j], t2sum);
}

// ---------------- pooled[g][j] = ((S/cnt) - mean)*rsqrt(var+eps)*gamma + beta ----------------
__global__ __launch_bounds__(HID) void k_pool(
        const float* __restrict__ Sgj, const float* __restrict__ T, const float* __restrict__ T2,
        const int* __restrict__ cnt, const float* __restrict__ gamma, const float* __restrict__ beta,
        float* __restrict__ pooled, int N) {
    const int j = threadIdx.x;
    const int g = blockIdx.x;
    float invN = 1.0f / (float)N;
    float mean = T[j] * invN;
    float var  = fmaf(-mean, mean, T2[j] * invN);
    float rinv = rsqrtf(var + BN_EPS);
    float c = (float)max(cnt[g], 1);
    pooled[g * HID + j] = (Sgj[g * HID + j] / c - mean) * rinv * gamma[j] + beta[j];
}

// ---------------- MLP: gelu([pooled,yfeat] @ W1 + b1) @ W2 + b2 -> sigmoid ----------------
__global__ __launch_bounds__(MLP1) void k_mlp(
        const float* __restrict__ pooled, const float* __restrict__ yfeat,
        const float* __restrict__ W1, const float* __restrict__ b1,
        const float* __restrict__ W2, const float* __restrict__ b2,
        float* __restrict__ out) {
    __shared__ float gv[HID + ADDF];
    __shared__ float hid[MLP1];
    const int g = blockIdx.x;
    const int t = threadIdx.x;

    for (int k = t; k < HID; k += MLP1) gv[k] = pooled[g * HID + k];
    if (t < ADDF) gv[HID + t] = yfeat[g * ADDF + t];
    __syncthreads();

    float acc = b1[t];
    #pragma unroll 8
    for (int k = 0; k < HID + ADDF; ++k)
        acc = fmaf(gv[k], W1[k * MLP1 + t], acc);
    hid[t] = gelu_exact(acc);
    __syncthreads();

    if (t < 2) {
        float o = b2[t];
        for (int k = 0; k < MLP1; ++k)
            o = fmaf(hid[k], W2[k * 2 + t], o);
        out[g * 2 + t] = 1.0f / (1.0f + expf(-o));
    }
}

extern "C" void kernel_launch(void* const* d_in, const int* in_sizes, int n_in,
                              void* d_out, int out_size, void* d_ws, size_t ws_size,
                              hipStream_t stream) {
    const float* x     = (const float*)d_in[0];
    const int*   edge  = (const int*)  d_in[1];
    const int*   batch = (const int*)  d_in[2];
    const float* yfeat = (const float*)d_in[3];
    const float* Wc    = (const float*)d_in[4];
    const float* bc    = (const float*)d_in[5];
    const float* gamma = (const float*)d_in[6];
    const float* beta  = (const float*)d_in[7];
    const float* W1    = (const float*)d_in[8];
    const float* b1    = (const float*)d_in[9];
    const float* W2    = (const float*)d_in[10];
    const float* b2    = (const float*)d_in[11];
    float* out = (float*)d_out;

    const int N = in_sizes[0];          // 100000
    const int E = in_sizes[1] / 2;      // 1600000
    const int G = in_sizes[3] / ADDF;   // 256

    const int* src = edge;              // edge_index[0]
    const int* dst = edge + E;          // edge_index[1]

    // ---- workspace layout (floats) ----
    float* ws    = (float*)d_ws;
    float* deg   = ws;                    // [N]  -> dinv in place
    float* agg   = deg + N;               // [N]
    float* s     = agg + N;               // [N]
    float* Sgj   = s + N;                 // [G*HID]
    float* T     = Sgj + (size_t)G * HID; // [HID]
    float* T2    = T + HID;               // [HID]
    int*   cnt   = (int*)(T2 + HID);      // [G]
    float* pooled= (float*)(cnt + G);     // [G*HID]

    const int zeroCount = 3 * N + G * HID + 2 * HID + G;  // everything up to (incl.) cnt

    k_zero<<<512, 256, 0, stream>>>(ws, zeroCount);
    k_deg<<<(E + 255) / 256, 256, 0, stream>>>(dst, deg, E);
    k_dinv<<<(N + 255) / 256, 256, 0, stream>>>(deg, N);
    k_scatter<<<(E + 255) / 256, 256, 0, stream>>>(src, dst, x, deg /*=dinv*/, agg, E);
    k_node<<<(N + 255) / 256, 256, 0, stream>>>(x, deg, agg, batch, s, cnt, N);
    k_gelu_acc<<<(N + CHUNK - 1) / CHUNK, HID, 0, stream>>>(s, batch, Wc, bc, Sgj, T, T2, N);
    k_pool<<<G, HID, 0, stream>>>(Sgj, T, T2, cnt, gamma, beta, pooled, N);
    k_mlp<<<G, MLP1, 0, stream>>>(pooled, yfeat, W1, b1, W2, b2, out);
}

// Round 2
// 235.170 us; speedup vs baseline: 1.5988x; 1.5988x over previous
//
#include <hip/hip_runtime.h>
#include <hip/hip_bf16.h>

#define HID 256
#define ADDF 7
#define MLP1 128
#define BN_EPS 1e-5f
#define INV_SQRT2 0.70710678118654752f

__device__ __forceinline__ float gelu_exact(float z) {
    return 0.5f * z * (1.0f + erff(z * INV_SQRT2));
}

// ---------------- zero workspace ----------------
__global__ void k_zero(float* p, int n) {
    for (int i = blockIdx.x * blockDim.x + threadIdx.x; i < n; i += gridDim.x * blockDim.x)
        p[i] = 0.0f;
}

// ---------------- degree: deg[dst] += 1 per edge ----------------
__global__ void k_deg(const int* __restrict__ dst, float* __restrict__ deg, int E) {
    int i = blockIdx.x * blockDim.x + threadIdx.x;
    if (i < E) atomicAdd(&deg[dst[i]], 1.0f);
}

// ---------------- dinv[i] = rsqrt(deg[i] + 1 /*self loop*/) ----------------
__global__ void k_dinv(float* __restrict__ deg, int N) {
    int i = blockIdx.x * blockDim.x + threadIdx.x;
    if (i < N) {
        float d = deg[i] + 1.0f;   // self-loop; always >= 1
        deg[i] = rsqrtf(d);        // in-place -> dinv
    }
}

// ---------------- agg[dst] += x[src] * dinv[src] ----------------
__global__ void k_scatter(const int* __restrict__ src, const int* __restrict__ dst,
                          const float* __restrict__ x, const float* __restrict__ dinv,
                          float* __restrict__ agg, int E) {
    int i = blockIdx.x * blockDim.x + threadIdx.x;
    if (i < E) {
        int s = src[i];
        atomicAdd(&agg[dst[i]], x[s] * dinv[s]);
    }
}

// ---------------- counts via binary search over sorted batch ----------------
__global__ void k_counts(const int* __restrict__ batch, int* __restrict__ cnt, int N, int G) {
    int g = blockIdx.x * blockDim.x + threadIdx.x;
    if (g >= G) return;
    int lo = 0, hi = N;
    while (lo < hi) { int mid = (lo + hi) >> 1; if (batch[mid] < g) lo = mid + 1; else hi = mid; }
    int start = lo;
    lo = 0; hi = N;
    while (lo < hi) { int mid = (lo + hi) >> 1; if (batch[mid] < g + 1) lo = mid + 1; else hi = mid; }
    cnt[g] = lo - start;
}

// ---------------- heavy: s computed inline; h = gelu(s*a_j + b_j); accumulate ----------------
#define CHUNK 128
__global__ __launch_bounds__(HID) void k_gelu_acc(
        const float* __restrict__ x, const float* __restrict__ dinv,
        const float* __restrict__ agg, const int* __restrict__ batch,
        const float* __restrict__ Wc, const float* __restrict__ bc,
        float* __restrict__ Sgj, float* __restrict__ T, float* __restrict__ T2, int N) {
    __shared__ float sh_s[CHUNK];
    __shared__ int   sh_b[CHUNK];
    const int j = threadIdx.x;               // feature 0..255
    const int base = blockIdx.x * CHUNK;
    const int count = min(CHUNK, N - base);

    if (j < count) {
        int i = base + j;
        float di = dinv[i];
        sh_s[j] = di * (agg[i] + x[i] * di);   // fused k_node
        sh_b[j] = batch[i];
    }
    __syncthreads();

    const float a = Wc[j];
    const float b = bc[j];
    float tsum = 0.f, t2sum = 0.f, gsum = 0.f;
    int gid = sh_b[0];

    for (int n = 0; n < count; ++n) {
        float z = fmaf(sh_s[n], a, b);
        float h = gelu_exact(z);
        tsum  += h;
        t2sum += h * h;
        int bg = sh_b[n];
        if (bg != gid) {                      // batch is sorted -> rare flush
            atomicAdd(&Sgj[gid * HID + j], gsum);
            gsum = 0.f;
            gid = bg;
        }
        gsum += h;
    }
    atomicAdd(&Sgj[gid * HID + j], gsum);
    atomicAdd(&T[j],  tsum);
    atomicAdd(&T2[j], t2sum);
}

// ---------------- pooled[g][j] = ((S/cnt) - mean)*rsqrt(var+eps)*gamma + beta ----------------
__global__ __launch_bounds__(HID) void k_pool(
        const float* __restrict__ Sgj, const float* __restrict__ T, const float* __restrict__ T2,
        const int* __restrict__ cnt, const float* __restrict__ gamma, const float* __restrict__ beta,
        float* __restrict__ pooled, int N) {
    const int j = threadIdx.x;
    const int g = blockIdx.x;
    float invN = 1.0f / (float)N;
    float mean = T[j] * invN;
    float var  = fmaf(-mean, mean, T2[j] * invN);
    float rinv = rsqrtf(var + BN_EPS);
    float c = (float)max(cnt[g], 1);
    pooled[g * HID + j] = (Sgj[g * HID + j] / c - mean) * rinv * gamma[j] + beta[j];
}

// ---------------- MLP: gelu([pooled,yfeat] @ W1 + b1) @ W2 + b2 -> sigmoid ----------------
__global__ __launch_bounds__(MLP1) void k_mlp(
        const float* __restrict__ pooled, const float* __restrict__ yfeat,
        const float* __restrict__ W1, const float* __restrict__ b1,
        const float* __restrict__ W2, const float* __restrict__ b2,
        float* __restrict__ out) {
    __shared__ float gv[HID + ADDF];
    __shared__ float hid[MLP1];
    const int g = blockIdx.x;
    const int t = threadIdx.x;

    for (int k = t; k < HID; k += MLP1) gv[k] = pooled[g * HID + k];
    if (t < ADDF) gv[HID + t] = yfeat[g * ADDF + t];
    __syncthreads();

    float acc = b1[t];
    #pragma unroll 8
    for (int k = 0; k < HID + ADDF; ++k)
        acc = fmaf(gv[k], W1[k * MLP1 + t], acc);
    hid[t] = gelu_exact(acc);
    __syncthreads();

    if (t < 2) {
        float o = b2[t];
        for (int k = 0; k < MLP1; ++k)
            o = fmaf(hid[k], W2[k * 2 + t], o);
        out[g * 2 + t] = 1.0f / (1.0f + expf(-o));
    }
}

extern "C" void kernel_launch(void* const* d_in, const int* in_sizes, int n_in,
                              void* d_out, int out_size, void* d_ws, size_t ws_size,
                              hipStream_t stream) {
    const float* x     = (const float*)d_in[0];
    const int*   edge  = (const int*)  d_in[1];
    const int*   batch = (const int*)  d_in[2];
    const float* yfeat = (const float*)d_in[3];
    const float* Wc    = (const float*)d_in[4];
    const float* bc    = (const float*)d_in[5];
    const float* gamma = (const float*)d_in[6];
    const float* beta  = (const float*)d_in[7];
    const float* W1    = (const float*)d_in[8];
    const float* b1    = (const float*)d_in[9];
    const float* W2    = (const float*)d_in[10];
    const float* b2    = (const float*)d_in[11];
    float* out = (float*)d_out;

    const int N = in_sizes[0];          // 100000
    const int E = in_sizes[1] / 2;      // 1600000
    const int G = in_sizes[3] / ADDF;   // 256

    const int* src = edge;              // edge_index[0]
    const int* dst = edge + E;          // edge_index[1]

    // ---- workspace layout (floats) ----
    // zeroed region first: deg[N], agg[N], Sgj[G*HID], T[HID], T2[HID]
    float* ws    = (float*)d_ws;
    float* deg   = ws;                     // [N]  -> dinv in place
    float* agg   = deg + N;                // [N]
    float* Sgj   = agg + N;                // [G*HID]
    float* T     = Sgj + (size_t)G * HID;  // [HID]
    float* T2    = T + HID;                // [HID]
    int*   cnt   = (int*)(T2 + HID);       // [G]   (written directly, no zero)
    float* pooled= (float*)(cnt + G);      // [G*HID]

    const int zeroCount = 2 * N + G * HID + 2 * HID;

    k_zero<<<512, 256, 0, stream>>>(ws, zeroCount);
    k_deg<<<(E + 255) / 256, 256, 0, stream>>>(dst, deg, E);
    k_dinv<<<(N + 255) / 256, 256, 0, stream>>>(deg, N);
    k_scatter<<<(E + 255) / 256, 256, 0, stream>>>(src, dst, x, deg /*=dinv*/, agg, E);
    k_counts<<<1, 256, 0, stream>>>(batch, cnt, N, G);
    k_gelu_acc<<<(N + CHUNK - 1) / CHUNK, HID, 0, stream>>>(x, deg, agg, batch, Wc, bc, Sgj, T, T2, N);
    k_pool<<<G, HID, 0, stream>>>(Sgj, T, T2, cnt, gamma, beta, pooled, N);
    k_mlp<<<G, MLP1, 0, stream>>>(pooled, yfeat, W1, b1, W2, b2, out);
}

// Round 4
// 126.255 us; speedup vs baseline: 2.9780x; 1.8627x over previous
//
#include <hip/hip_runtime.h>
#include <hip/hip_bf16.h>

#define HID 256
#define ADDF 7
#define MLP1 128
#define BN_EPS 1e-5f
#define INV_SQRT2 0.70710678118654752f

// ---- binning parameters ----
#define NBINS 1024
#define BINW  98            // nodes per bin; NBINS*BINW = 100352 >= N
#define BINCAP 2048         // capacity per bin (mean 1562, +12 sigma)
#define PLACE_CHUNK 4096

__device__ __forceinline__ float gelu_exact(float z) {
    return 0.5f * z * (1.0f + erff(z * INV_SQRT2));
}

// ---------------- zero + cursor init ----------------
__global__ void k_init(float* zp, int nz, int* binCursor) {
    int i = blockIdx.x * blockDim.x + threadIdx.x;
    for (int k = i; k < nz; k += gridDim.x * blockDim.x) zp[k] = 0.0f;
    if (i < NBINS) binCursor[i] = i * BINCAP;
}

// ---------------- place edges into dst-range bins ----------------
__global__ __launch_bounds__(256) void k_place(
        const int* __restrict__ src, const int* __restrict__ dst,
        int* __restrict__ binCursor, int* __restrict__ recs, int E) {
    __shared__ int hist[NBINS];
    const int t = threadIdx.x;
    for (int b = t; b < NBINS; b += 256) hist[b] = 0;
    __syncthreads();

    const int s0 = blockIdx.x * PLACE_CHUNK;
    const int e0 = min(s0 + PLACE_CHUNK, E);

    for (int i = s0 + t; i < e0; i += 256)
        atomicAdd(&hist[dst[i] / BINW], 1);
    __syncthreads();

    // reserve global space per bin; hist[b] becomes this block's running cursor
    for (int b = t; b < NBINS; b += 256) {
        int c = hist[b];
        hist[b] = c ? atomicAdd(&binCursor[b], c) : 0;
    }
    __syncthreads();

    for (int i = s0 + t; i < e0; i += 256) {
        int d = dst[i];
        int bin = d / BINW;
        int pos = atomicAdd(&hist[bin], 1);
        recs[pos] = ((d - bin * BINW) << 17) | src[i];   // src < 2^17, dl < 98
    }
}

// ---------------- per-bin degree -> dinv ----------------
__global__ __launch_bounds__(256) void k_degdinv(
        const int* __restrict__ recs, const int* __restrict__ binCursor,
        float* __restrict__ dinv, int N) {
    __shared__ int degL[BINW];
    const int b = blockIdx.x;
    const int t = threadIdx.x;
    if (t < BINW) degL[t] = 0;
    __syncthreads();

    const int start = b * BINCAP;
    const int end   = binCursor[b];
    for (int i = start + t; i < end; i += 256)
        atomicAdd(&degL[recs[i] >> 17], 1);
    __syncthreads();

    int node = b * BINW + t;
    if (t < BINW && node < N)
        dinv[node] = rsqrtf((float)degL[t] + 1.0f);   // +1 self-loop
}

// ---------------- per-bin scatter: s[i] = dinv_i*(sum x_src*dinv_src + x_i*dinv_i) ----------------
__global__ __launch_bounds__(256) void k_aggs(
        const int* __restrict__ recs, const int* __restrict__ binCursor,
        const float* __restrict__ x, const float* __restrict__ dinv,
        float* __restrict__ s, int N) {
    __shared__ float aggL[BINW];
    const int b = blockIdx.x;
    const int t = threadIdx.x;
    if (t < BINW) aggL[t] = 0.0f;
    __syncthreads();

    const int start = b * BINCAP;
    const int end   = binCursor[b];
    for (int i = start + t; i < end; i += 256) {
        int rec = recs[i];
        int sN  = rec & 0x1FFFF;
        atomicAdd(&aggL[rec >> 17], x[sN] * dinv[sN]);
    }
    __syncthreads();

    int node = b * BINW + t;
    if (t < BINW && node < N) {
        float di = dinv[node];
        s[node] = di * (aggL[t] + x[node] * di);
    }
}

// ---------------- counts via binary search over sorted batch ----------------
__global__ void k_counts(const int* __restrict__ batch, int* __restrict__ cnt, int N, int G) {
    int g = blockIdx.x * blockDim.x + threadIdx.x;
    if (g >= G) return;
    int lo = 0, hi = N;
    while (lo < hi) { int mid = (lo + hi) >> 1; if (batch[mid] < g) lo = mid + 1; else hi = mid; }
    int start = lo;
    lo = 0; hi = N;
    while (lo < hi) { int mid = (lo + hi) >> 1; if (batch[mid] < g + 1) lo = mid + 1; else hi = mid; }
    cnt[g] = lo - start;
}

// ---------------- heavy: h = gelu(s*a_j + b_j); accumulate S[g][j], T[j], T2[j] ----------------
#define CHUNK 128
__global__ __launch_bounds__(HID) void k_gelu_acc(
        const float* __restrict__ s, const int* __restrict__ batch,
        const float* __restrict__ Wc, const float* __restrict__ bc,
        float* __restrict__ Sgj, float* __restrict__ T, float* __restrict__ T2, int N) {
    __shared__ float sh_s[CHUNK];
    __shared__ int   sh_b[CHUNK];
    const int j = threadIdx.x;               // feature 0..255
    const int base = blockIdx.x * CHUNK;
    const int count = min(CHUNK, N - base);

    if (j < count) {
        sh_s[j] = s[base + j];
        sh_b[j] = batch[base + j];
    }
    __syncthreads();

    const float a = Wc[j];
    const float b = bc[j];
    float tsum = 0.f, t2sum = 0.f, gsum = 0.f;
    int gid = sh_b[0];

    for (int n = 0; n < count; ++n) {
        float z = fmaf(sh_s[n], a, b);
        float h = gelu_exact(z);
        tsum  += h;
        t2sum += h * h;
        int bg = sh_b[n];
        if (bg != gid) {                      // batch sorted -> rare flush
            atomicAdd(&Sgj[gid * HID + j], gsum);
            gsum = 0.f;
            gid = bg;
        }
        gsum += h;
    }
    atomicAdd(&Sgj[gid * HID + j], gsum);
    atomicAdd(&T[j],  tsum);
    atomicAdd(&T2[j], t2sum);
}

// ---------------- pooled + BN finalize ----------------
__global__ __launch_bounds__(HID) void k_pool(
        const float* __restrict__ Sgj, const float* __restrict__ T, const float* __restrict__ T2,
        const int* __restrict__ cnt, const float* __restrict__ gamma, const float* __restrict__ beta,
        float* __restrict__ pooled, int N) {
    const int j = threadIdx.x;
    const int g = blockIdx.x;
    float invN = 1.0f / (float)N;
    float mean = T[j] * invN;
    float var  = fmaf(-mean, mean, T2[j] * invN);
    float rinv = rsqrtf(var + BN_EPS);
    float c = (float)max(cnt[g], 1);
    pooled[g * HID + j] = (Sgj[g * HID + j] / c - mean) * rinv * gamma[j] + beta[j];
}

// ---------------- MLP ----------------
__global__ __launch_bounds__(MLP1) void k_mlp(
        const float* __restrict__ pooled, const float* __restrict__ yfeat,
        const float* __restrict__ W1, const float* __restrict__ b1,
        const float* __restrict__ W2, const float* __restrict__ b2,
        float* __restrict__ out) {
    __shared__ float gv[HID + ADDF];
    __shared__ float hid[MLP1];
    const int g = blockIdx.x;
    const int t = threadIdx.x;

    for (int k = t; k < HID; k += MLP1) gv[k] = pooled[g * HID + k];
    if (t < ADDF) gv[HID + t] = yfeat[g * ADDF + t];
    __syncthreads();

    float acc = b1[t];
    #pragma unroll 8
    for (int k = 0; k < HID + ADDF; ++k)
        acc = fmaf(gv[k], W1[k * MLP1 + t], acc);
    hid[t] = gelu_exact(acc);
    __syncthreads();

    if (t < 2) {
        float o = b2[t];
        for (int k = 0; k < MLP1; ++k)
            o = fmaf(hid[k], W2[k * 2 + t], o);
        out[g * 2 + t] = 1.0f / (1.0f + expf(-o));
    }
}

// ================= fallback (round-2 path) kernels =================
__global__ void k_zero(float* p, int n) {
    for (int i = blockIdx.x * blockDim.x + threadIdx.x; i < n; i += gridDim.x * blockDim.x)
        p[i] = 0.0f;
}
__global__ void k_deg_fb(const int* __restrict__ dst, float* __restrict__ deg, int E) {
    int i = blockIdx.x * blockDim.x + threadIdx.x;
    if (i < E) atomicAdd(&deg[dst[i]], 1.0f);
}
__global__ void k_dinv_fb(float* __restrict__ deg, int N) {
    int i = blockIdx.x * blockDim.x + threadIdx.x;
    if (i < N) deg[i] = rsqrtf(deg[i] + 1.0f);
}
__global__ void k_scatter_fb(const int* __restrict__ src, const int* __restrict__ dst,
                             const float* __restrict__ x, const float* __restrict__ dinv,
                             float* __restrict__ agg, int E) {
    int i = blockIdx.x * blockDim.x + threadIdx.x;
    if (i < E) { int s = src[i]; atomicAdd(&agg[dst[i]], x[s] * dinv[s]); }
}
__global__ void k_node_fb(const float* __restrict__ x, const float* __restrict__ dinv,
                          const float* __restrict__ agg, float* __restrict__ s, int N) {
    int i = blockIdx.x * blockDim.x + threadIdx.x;
    if (i < N) { float di = dinv[i]; s[i] = di * (agg[i] + x[i] * di); }
}

extern "C" void kernel_launch(void* const* d_in, const int* in_sizes, int n_in,
                              void* d_out, int out_size, void* d_ws, size_t ws_size,
                              hipStream_t stream) {
    const float* x     = (const float*)d_in[0];
    const int*   edge  = (const int*)  d_in[1];
    const int*   batch = (const int*)  d_in[2];
    const float* yfeat = (const float*)d_in[3];
    const float* Wc    = (const float*)d_in[4];
    const float* bc    = (const float*)d_in[5];
    const float* gamma = (const float*)d_in[6];
    const float* beta  = (const float*)d_in[7];
    const float* W1    = (const float*)d_in[8];
    const float* b1    = (const float*)d_in[9];
    const float* W2    = (const float*)d_in[10];
    const float* b2    = (const float*)d_in[11];
    float* out = (float*)d_out;

    const int N = in_sizes[0];          // 100000
    const int E = in_sizes[1] / 2;      // 1600000
    const int G = in_sizes[3] / ADDF;   // 256

    const int* srcIdx = edge;           // edge_index[0]
    const int* dstIdx = edge + E;       // edge_index[1]

    // ---- workspace layout (floats/ints) ----
    float* ws     = (float*)d_ws;
    float* Sgj    = ws;                           // [G*HID] zeroed
    float* T      = Sgj + (size_t)G * HID;        // [HID]   zeroed
    float* T2     = T + HID;                      // [HID]   zeroed
    int*   cnt    = (int*)(T2 + HID);             // [G]
    int*   binCur = cnt + G;                      // [NBINS]
    float* dinv   = (float*)(binCur + NBINS);     // [N]
    float* s      = dinv + N;                     // [N]
    float* pooled = s + N;                        // [G*HID]
    float* tail   = pooled + (size_t)G * HID;     // binned: recs[NBINS*BINCAP]; fallback: agg[N]
    int*   recs   = (int*)tail;

    const size_t baseFloats = (size_t)G * HID + 2 * HID + G + NBINS + 2 * (size_t)N
                              + (size_t)G * HID;
    const size_t needBinned   = (baseFloats + (size_t)NBINS * BINCAP) * 4;
    const int zeroCount = G * HID + 2 * HID;

    if (ws_size >= needBinned && N < (1 << 17)) {
        // ---- binned path: no global atomics over edges ----
        k_init<<<512, 256, 0, stream>>>(Sgj, zeroCount, binCur);
        k_place<<<(E + PLACE_CHUNK - 1) / PLACE_CHUNK, 256, 0, stream>>>(srcIdx, dstIdx, binCur, recs, E);
        k_degdinv<<<NBINS, 256, 0, stream>>>(recs, binCur, dinv, N);
        k_aggs<<<NBINS, 256, 0, stream>>>(recs, binCur, x, dinv, s, N);
    } else {
        // ---- fallback: global-atomic path (round-2) ----
        float* deg = dinv;      // reuse dinv slot
        float* agg = tail;      // [N] after pooled
        k_zero<<<512, 256, 0, stream>>>(Sgj, zeroCount);
        k_zero<<<512, 256, 0, stream>>>(deg, N);
        k_zero<<<512, 256, 0, stream>>>(agg, N);
        k_deg_fb<<<(E + 255) / 256, 256, 0, stream>>>(dstIdx, deg, E);
        k_dinv_fb<<<(N + 255) / 256, 256, 0, stream>>>(deg, N);
        k_scatter_fb<<<(E + 255) / 256, 256, 0, stream>>>(srcIdx, dstIdx, x, deg, agg, E);
        k_node_fb<<<(N + 255) / 256, 256, 0, stream>>>(x, deg, agg, s, N);
    }

    k_counts<<<1, 256, 0, stream>>>(batch, cnt, N, G);
    k_gelu_acc<<<(N + CHUNK - 1) / CHUNK, HID, 0, stream>>>(s, batch, Wc, bc, Sgj, T, T2, N);
    k_pool<<<G, HID, 0, stream>>>(Sgj, T, T2, cnt, gamma, beta, pooled, N);
    k_mlp<<<G, MLP1, 0, stream>>>(pooled, yfeat, W1, b1, W2, b2, out);
}

// Round 5
// 109.915 us; speedup vs baseline: 3.4207x; 1.1487x over previous
//
#include <hip/hip_runtime.h>
#include <hip/hip_bf16.h>

#define HID 256
#define ADDF 7
#define MLP1 128
#define BN_EPS 1e-5f
#define INV_SQRT2 0.70710678118654752f

// ---- binning parameters ----
#define NBINS 1024
#define BINW  98              // nodes per bin; NBINS*BINW = 100352 >= N
#define BINCAP 2048           // capacity per bin (mean 1562, +12 sigma)
#define PLACE_CHUNK 32768
#define PLACE_THREADS 1024
#define NREP 8                // T/T2 replicas

__device__ __forceinline__ float gelu_exact(float z) {
    return 0.5f * z * (1.0f + erff(z * INV_SQRT2));
}

// ---------------- init: zero accumulators, init cursors, graph counts ----------------
__global__ void k_init(float* zp, int nz, int* binCursor,
                       const int* __restrict__ batch, int* __restrict__ cnt, int N, int G) {
    const int nzBlocks = (nz + 255) / 256;
    if ((int)blockIdx.x < nzBlocks) {
        int i = blockIdx.x * 256 + threadIdx.x;
        if (i < nz) zp[i] = 0.0f;
    } else {
        const int t = threadIdx.x;
        for (int b = t; b < NBINS; b += 256) binCursor[b] = b * BINCAP;
        int g = t;
        if (g < G) {
            int lo = 0, hi = N;
            while (lo < hi) { int mid = (lo + hi) >> 1; if (batch[mid] < g) lo = mid + 1; else hi = mid; }
            int start = lo;
            lo = 0; hi = N;
            while (lo < hi) { int mid = (lo + hi) >> 1; if (batch[mid] < g + 1) lo = mid + 1; else hi = mid; }
            cnt[g] = lo - start;
        }
    }
}

// ---------------- place edges into dst-range bins ----------------
__global__ __launch_bounds__(PLACE_THREADS) void k_place(
        const int* __restrict__ src, const int* __restrict__ dst,
        int* __restrict__ binCursor, int* __restrict__ recs, int E) {
    __shared__ int hist[NBINS];
    const int t = threadIdx.x;
    if (t < NBINS) hist[t] = 0;               // PLACE_THREADS == NBINS
    __syncthreads();

    const int s0 = blockIdx.x * PLACE_CHUNK;
    const int e0 = min(s0 + PLACE_CHUNK, E);

    for (int i = s0 + t; i < e0; i += PLACE_THREADS)
        atomicAdd(&hist[dst[i] / BINW], 1);
    __syncthreads();

    // staggered reservation: concurrent blocks hit different cache lines
    {
        int b = (t + (int)blockIdx.x * 64) & (NBINS - 1);
        int c = hist[b];
        hist[b] = c ? atomicAdd(&binCursor[b], c) : 0;
    }
    __syncthreads();

    for (int i = s0 + t; i < e0; i += PLACE_THREADS) {
        int d = dst[i];
        int bin = d / BINW;
        int pos = atomicAdd(&hist[bin], 1);
        recs[pos] = ((d - bin * BINW) << 17) | src[i];   // src < 2^17, dl < 98
    }
}

// ---------------- per-bin degree -> dinv ----------------
__global__ __launch_bounds__(256) void k_degdinv(
        const int* __restrict__ recs, const int* __restrict__ binCursor,
        float* __restrict__ dinv, int N) {
    __shared__ int degL[BINW];
    const int b = blockIdx.x;
    const int t = threadIdx.x;
    if (t < BINW) degL[t] = 0;
    __syncthreads();

    const int start = b * BINCAP;
    const int end   = binCursor[b];
    for (int i = start + t; i < end; i += 256)
        atomicAdd(&degL[recs[i] >> 17], 1);
    __syncthreads();

    int node = b * BINW + t;
    if (t < BINW && node < N)
        dinv[node] = rsqrtf((float)degL[t] + 1.0f);   // +1 self-loop
}

// ---------------- fused: per-bin agg -> s (LDS) -> gelu accumulate ----------------
__global__ __launch_bounds__(256) void k_aggs_gelu(
        const int* __restrict__ recs, const int* __restrict__ binCursor,
        const float* __restrict__ x, const float* __restrict__ dinv,
        const int* __restrict__ batch,
        const float* __restrict__ Wc, const float* __restrict__ bc,
        float* __restrict__ Sgj, float* __restrict__ Trep, float* __restrict__ T2rep,
        int N) {
    __shared__ float aggL[BINW];
    __shared__ float sh_s[BINW];
    __shared__ int   sh_b[BINW];
    const int b = blockIdx.x;
    const int t = threadIdx.x;
    if (t < BINW) aggL[t] = 0.0f;
    __syncthreads();

    const int start = b * BINCAP;
    const int end   = binCursor[b];
    for (int i = start + t; i < end; i += 256) {
        int rec = recs[i];
        int sN  = rec & 0x1FFFF;
        atomicAdd(&aggL[rec >> 17], x[sN] * dinv[sN]);
    }
    __syncthreads();

    const int node0 = b * BINW;
    const int count = min(BINW, N - node0);
    if (count <= 0) return;

    if (t < count) {
        int node = node0 + t;
        float di = dinv[node];
        sh_s[t] = di * (aggL[t] + x[node] * di);
        sh_b[t] = batch[node];
    }
    __syncthreads();

    const float a  = Wc[t];
    const float bb = bc[t];
    float tsum = 0.f, t2sum = 0.f, gsum = 0.f;
    int gid = sh_b[0];

    for (int n = 0; n < count; ++n) {
        float z = fmaf(sh_s[n], a, bb);
        float h = gelu_exact(z);
        tsum  += h;
        t2sum += h * h;
        int bg = sh_b[n];
        if (bg != gid) {                      // batch sorted -> rare flush
            atomicAdd(&Sgj[gid * HID + t], gsum);
            gsum = 0.f;
            gid = bg;
        }
        gsum += h;
    }
    atomicAdd(&Sgj[gid * HID + t], gsum);
    const int r = b & (NREP - 1);
    atomicAdd(&Trep [r * HID + t], tsum);
    atomicAdd(&T2rep[r * HID + t], t2sum);
}

// ---------------- pooled + BN finalize ----------------
__global__ __launch_bounds__(HID) void k_pool(
        const float* __restrict__ Sgj, const float* __restrict__ Trep, const float* __restrict__ T2rep,
        const int* __restrict__ cnt, const float* __restrict__ gamma, const float* __restrict__ beta,
        float* __restrict__ pooled, int N) {
    const int j = threadIdx.x;
    const int g = blockIdx.x;
    float Ts = 0.f, T2s = 0.f;
    #pragma unroll
    for (int r = 0; r < NREP; ++r) { Ts += Trep[r * HID + j]; T2s += T2rep[r * HID + j]; }
    float invN = 1.0f / (float)N;
    float mean = Ts * invN;
    float var  = fmaf(-mean, mean, T2s * invN);
    float rinv = rsqrtf(var + BN_EPS);
    float c = (float)max(cnt[g], 1);
    pooled[g * HID + j] = (Sgj[g * HID + j] / c - mean) * rinv * gamma[j] + beta[j];
}

// ---------------- MLP ----------------
__global__ __launch_bounds__(MLP1) void k_mlp(
        const float* __restrict__ pooled, const float* __restrict__ yfeat,
        const float* __restrict__ W1, const float* __restrict__ b1,
        const float* __restrict__ W2, const float* __restrict__ b2,
        float* __restrict__ out) {
    __shared__ float gv[HID + ADDF];
    __shared__ float hid[MLP1];
    const int g = blockIdx.x;
    const int t = threadIdx.x;

    for (int k = t; k < HID; k += MLP1) gv[k] = pooled[g * HID + k];
    if (t < ADDF) gv[HID + t] = yfeat[g * ADDF + t];
    __syncthreads();

    float acc = b1[t];
    #pragma unroll 8
    for (int k = 0; k < HID + ADDF; ++k)
        acc = fmaf(gv[k], W1[k * MLP1 + t], acc);
    hid[t] = gelu_exact(acc);
    __syncthreads();

    if (t < 2) {
        float o = b2[t];
        for (int k = 0; k < MLP1; ++k)
            o = fmaf(hid[k], W2[k * 2 + t], o);
        out[g * 2 + t] = 1.0f / (1.0f + expf(-o));
    }
}

// ================= fallback (global-atomic) kernels =================
__global__ void k_zero(float* p, int n) {
    for (int i = blockIdx.x * blockDim.x + threadIdx.x; i < n; i += gridDim.x * blockDim.x)
        p[i] = 0.0f;
}
__global__ void k_deg_fb(const int* __restrict__ dst, float* __restrict__ deg, int E) {
    int i = blockIdx.x * blockDim.x + threadIdx.x;
    if (i < E) atomicAdd(&deg[dst[i]], 1.0f);
}
__global__ void k_dinv_fb(float* __restrict__ deg, int N) {
    int i = blockIdx.x * blockDim.x + threadIdx.x;
    if (i < N) deg[i] = rsqrtf(deg[i] + 1.0f);
}
__global__ void k_scatter_fb(const int* __restrict__ src, const int* __restrict__ dst,
                             const float* __restrict__ x, const float* __restrict__ dinv,
                             float* __restrict__ agg, int E) {
    int i = blockIdx.x * blockDim.x + threadIdx.x;
    if (i < E) { int s = src[i]; atomicAdd(&agg[dst[i]], x[s] * dinv[s]); }
}
#define CHUNK_FB 64
__global__ __launch_bounds__(HID) void k_gelu_fb(
        const float* __restrict__ x, const float* __restrict__ dinv,
        const float* __restrict__ agg, const int* __restrict__ batch,
        const float* __restrict__ Wc, const float* __restrict__ bc,
        float* __restrict__ Sgj, float* __restrict__ Trep, float* __restrict__ T2rep, int N) {
    __shared__ float sh_s[CHUNK_FB];
    __shared__ int   sh_b[CHUNK_FB];
    const int j = threadIdx.x;
    const int base = blockIdx.x * CHUNK_FB;
    const int count = min(CHUNK_FB, N - base);
    if (j < count) {
        int i = base + j;
        float di = dinv[i];
        sh_s[j] = di * (agg[i] + x[i] * di);
        sh_b[j] = batch[i];
    }
    __syncthreads();
    const float a = Wc[j];
    const float b = bc[j];
    float tsum = 0.f, t2sum = 0.f, gsum = 0.f;
    int gid = sh_b[0];
    for (int n = 0; n < count; ++n) {
        float z = fmaf(sh_s[n], a, b);
        float h = gelu_exact(z);
        tsum += h; t2sum += h * h;
        int bg = sh_b[n];
        if (bg != gid) { atomicAdd(&Sgj[gid * HID + j], gsum); gsum = 0.f; gid = bg; }
        gsum += h;
    }
    atomicAdd(&Sgj[gid * HID + j], gsum);
    const int r = blockIdx.x & (NREP - 1);
    atomicAdd(&Trep [r * HID + j], tsum);
    atomicAdd(&T2rep[r * HID + j], t2sum);
}

extern "C" void kernel_launch(void* const* d_in, const int* in_sizes, int n_in,
                              void* d_out, int out_size, void* d_ws, size_t ws_size,
                              hipStream_t stream) {
    const float* x     = (const float*)d_in[0];
    const int*   edge  = (const int*)  d_in[1];
    const int*   batch = (const int*)  d_in[2];
    const float* yfeat = (const float*)d_in[3];
    const float* Wc    = (const float*)d_in[4];
    const float* bc    = (const float*)d_in[5];
    const float* gamma = (const float*)d_in[6];
    const float* beta  = (const float*)d_in[7];
    const float* W1    = (const float*)d_in[8];
    const float* b1    = (const float*)d_in[9];
    const float* W2    = (const float*)d_in[10];
    const float* b2    = (const float*)d_in[11];
    float* out = (float*)d_out;

    const int N = in_sizes[0];          // 100000
    const int E = in_sizes[1] / 2;      // 1600000
    const int G = in_sizes[3] / ADDF;   // 256

    const int* srcIdx = edge;           // edge_index[0]
    const int* dstIdx = edge + E;       // edge_index[1]

    // ---- workspace layout ----
    float* ws     = (float*)d_ws;
    float* Sgj    = ws;                           // [G*HID]   zeroed
    float* Trep   = Sgj + (size_t)G * HID;        // [NREP*HID] zeroed
    float* T2rep  = Trep + NREP * HID;            // [NREP*HID] zeroed
    int*   cnt    = (int*)(T2rep + NREP * HID);   // [G]
    int*   binCur = cnt + G;                      // [NBINS]
    float* dinv   = (float*)(binCur + NBINS);     // [N]
    float* sbuf   = dinv + N;                     // [N] (fallback only)
    float* pooled = sbuf + N;                     // [G*HID]
    float* tail   = pooled + (size_t)G * HID;     // binned: recs; fallback: agg[N]
    int*   recs   = (int*)tail;

    const size_t baseFloats = (size_t)G * HID + 2 * NREP * HID + G + NBINS
                              + 2 * (size_t)N + (size_t)G * HID;
    const size_t needBinned = (baseFloats + (size_t)NBINS * BINCAP) * 4;
    const int zeroCount = G * HID + 2 * NREP * HID;
    const int initBlocks = (zeroCount + 255) / 256 + 1;

    if (ws_size >= needBinned && N < (1 << 17)) {
        // ---- binned path: no per-edge global atomics ----
        k_init<<<initBlocks, 256, 0, stream>>>(Sgj, zeroCount, binCur, batch, cnt, N, G);
        k_place<<<(E + PLACE_CHUNK - 1) / PLACE_CHUNK, PLACE_THREADS, 0, stream>>>(srcIdx, dstIdx, binCur, recs, E);
        k_degdinv<<<NBINS, 256, 0, stream>>>(recs, binCur, dinv, N);
        k_aggs_gelu<<<NBINS, 256, 0, stream>>>(recs, binCur, x, dinv, batch, Wc, bc, Sgj, Trep, T2rep, N);
    } else {
        // ---- fallback: global-atomic path ----
        float* deg = dinv;
        float* agg = tail;
        k_init<<<initBlocks, 256, 0, stream>>>(Sgj, zeroCount, binCur, batch, cnt, N, G);
        k_zero<<<512, 256, 0, stream>>>(deg, N);
        k_zero<<<512, 256, 0, stream>>>(agg, N);
        k_deg_fb<<<(E + 255) / 256, 256, 0, stream>>>(dstIdx, deg, E);
        k_dinv_fb<<<(N + 255) / 256, 256, 0, stream>>>(deg, N);
        k_scatter_fb<<<(E + 255) / 256, 256, 0, stream>>>(srcIdx, dstIdx, x, deg, agg, E);
        k_gelu_fb<<<(N + CHUNK_FB - 1) / CHUNK_FB, HID, 0, stream>>>(x, deg, agg, batch, Wc, bc, Sgj, Trep, T2rep, N);
    }

    k_pool<<<G, HID, 0, stream>>>(Sgj, Trep, T2rep, cnt, gamma, beta, pooled, N);
    k_mlp<<<G, MLP1, 0, stream>>>(pooled, yfeat, W1, b1, W2, b2, out);
}

// Round 6
// 93.914 us; speedup vs baseline: 4.0036x; 1.1704x over previous
//
#include <hip/hip_runtime.h>
#include <hip/hip_bf16.h>

#define HID 256
#define ADDF 7
#define MLP1 128
#define BN_EPS 1e-5f
#define INV_SQRT2 0.70710678118654752f
#define NREP 8                // T/T2 replicas

// ---- tier-1: two-level binning parameters ----
#define NCB 64                // coarse bins
#define CBW 1568              // nodes per coarse bin (= 16*98); 64*1568 = 100352 >= N
#define CBCAP 28672           // recs capacity per coarse bin (mean 25000, +23 sigma)
#define PC1 8192              // edges per place block
#define P1T 512               // place threads
#define NSB 8                 // sub-blocks per coarse bin (= partial replicas)
#define GCH 98                // nodes per gelu block

// ---- tier-2 (fallback): one-level binning parameters ----
#define NBINS 1024
#define BINW  98
#define BINCAP 2048
#define PLACE_CHUNK 32768
#define PLACE_THREADS 1024

__device__ __forceinline__ float gelu_exact(float z) {
    return 0.5f * z * (1.0f + erff(z * INV_SQRT2));
}

// tanh-form gelu: 0.5z(1+tanh(c0 z (1+c1 z^2))) = z*u/(u+1), u = exp(z*(2c0 + 2c0c1 z^2))
__device__ __forceinline__ float gelu_fast(float z) {
    float z2 = z * z;
    float y2 = z * fmaf(0.07135481627f, z2, 1.59576912161f);
    float u  = __expf(fminf(y2, 80.0f));
    return z * u * __builtin_amdgcn_rcpf(u + 1.0f);
}

// ---------------- init: zero accumulators, init cursors, graph counts ----------------
__global__ void k_init(float* zp, int nz, int* binCursor, int nCur, int cap,
                       const int* __restrict__ batch, int* __restrict__ cnt, int N, int G) {
    const int nzBlocks = (nz + 255) / 256;
    if ((int)blockIdx.x < nzBlocks) {
        int i = blockIdx.x * 256 + threadIdx.x;
        if (i < nz) zp[i] = 0.0f;
    } else {
        const int t = threadIdx.x;
        for (int b = t; b < nCur; b += 256) binCursor[b] = b * cap;
        int g = t;
        if (g < G) {
            int lo = 0, hi = N;
            while (lo < hi) { int mid = (lo + hi) >> 1; if (batch[mid] < g) lo = mid + 1; else hi = mid; }
            int start = lo;
            lo = 0; hi = N;
            while (lo < hi) { int mid = (lo + hi) >> 1; if (batch[mid] < g + 1) lo = mid + 1; else hi = mid; }
            cnt[g] = lo - start;
        }
    }
}

// ================= tier-1 kernels =================

// ---------------- coarse place: 64 bins, per-wave cursors ----------------
__global__ __launch_bounds__(P1T) void k_place1(
        const int* __restrict__ src, const int* __restrict__ dst,
        int* __restrict__ binCur, int* __restrict__ recs, int E) {
    __shared__ int histR[8][NCB];            // per-wave histograms/cursors
    const int t = threadIdx.x;
    const int w = t >> 6;
    for (int b = t; b < 8 * NCB; b += P1T) (&histR[0][0])[b] = 0;
    __syncthreads();

    const int s0 = blockIdx.x * PC1;
    const int e0 = min(s0 + PC1, E);

    for (int i = s0 + t; i < e0; i += P1T)
        atomicAdd(&histR[w][dst[i] / CBW], 1);
    __syncthreads();

    if (t < NCB) {
        int b = (t + (int)blockIdx.x) & (NCB - 1);   // stagger reservation
        int tot = 0;
        #pragma unroll
        for (int ww = 0; ww < 8; ++ww) tot += histR[ww][b];
        int base = tot ? atomicAdd(&binCur[b], tot) : 0;
        #pragma unroll
        for (int ww = 0; ww < 8; ++ww) { int c = histR[ww][b]; histR[ww][b] = base; base += c; }
    }
    __syncthreads();

    for (int i = s0 + t; i < e0; i += P1T) {
        int d = dst[i];
        int bin = d / CBW;
        int pos = atomicAdd(&histR[w][bin], 1);
        recs[pos] = ((d - bin * CBW) << 17) | src[i];   // dl<1568 (11b), src<2^17
    }
}

// ---------------- per-(bin,sub-block) degree partials ----------------
__global__ __launch_bounds__(256) void k_deg2(
        const int* __restrict__ recs, const int* __restrict__ binCur,
        int* __restrict__ degP) {
    __shared__ int degL[CBW];
    const int cb = blockIdx.x >> 3;
    const int r  = blockIdx.x & 7;
    const int t  = threadIdx.x;
    for (int k = t; k < CBW; k += 256) degL[k] = 0;
    __syncthreads();

    const int start = cb * CBCAP;
    const int seg   = binCur[cb] - start;
    const int a0 = start + (seg * r)     / 8;
    const int a1 = start + (seg * (r+1)) / 8;
    for (int i = a0 + t; i < a1; i += 256)
        atomicAdd(&degL[recs[i] >> 17], 1);
    __syncthreads();

    int* outp = degP + (size_t)blockIdx.x * CBW;
    for (int k = t; k < CBW; k += 256) outp[k] = degL[k];
}

// ---------------- dinv = rsqrt(sum partials + 1) ----------------
__global__ void k_dinvk(const int* __restrict__ degP, float* __restrict__ dinv, int N) {
    int i = blockIdx.x * blockDim.x + threadIdx.x;
    if (i >= N) return;
    int cb = i / CBW, loc = i - cb * CBW;
    const int* p = degP + (size_t)cb * NSB * CBW + loc;
    int d = 1;
    #pragma unroll
    for (int r = 0; r < NSB; ++r) d += p[r * CBW];
    dinv[i] = rsqrtf((float)d);
}

// ---------------- per-(bin,sub-block) agg partials ----------------
__global__ __launch_bounds__(256) void k_agg2(
        const int* __restrict__ recs, const int* __restrict__ binCur,
        const float* __restrict__ x, const float* __restrict__ dinv,
        float* __restrict__ aggP) {
    __shared__ float aggL[CBW];
    const int cb = blockIdx.x >> 3;
    const int r  = blockIdx.x & 7;
    const int t  = threadIdx.x;
    for (int k = t; k < CBW; k += 256) aggL[k] = 0.0f;
    __syncthreads();

    const int start = cb * CBCAP;
    const int seg   = binCur[cb] - start;
    const int a0 = start + (seg * r)     / 8;
    const int a1 = start + (seg * (r+1)) / 8;
    for (int i = a0 + t; i < a1; i += 256) {
        int rec = recs[i];
        int sN  = rec & 0x1FFFF;
        atomicAdd(&aggL[rec >> 17], x[sN] * dinv[sN]);
    }
    __syncthreads();

    float* outp = aggP + (size_t)blockIdx.x * CBW;
    for (int k = t; k < CBW; k += 256) outp[k] = aggL[k];
}

// ---------------- gelu accumulate: s inline from partials, fast gelu, 2x unroll ----------------
__global__ __launch_bounds__(HID) void k_gelu(
        const float* __restrict__ x, const float* __restrict__ dinv,
        const float* __restrict__ aggP, const int* __restrict__ batch,
        const float* __restrict__ Wc, const float* __restrict__ bc,
        float* __restrict__ Sgj, float* __restrict__ Trep, float* __restrict__ T2rep, int N) {
    __shared__ float sh_s[GCH];
    __shared__ int   sh_b[GCH];
    const int c = blockIdx.x;
    const int t = threadIdx.x;
    const int base = c * GCH;
    const int count = min(GCH, N - base);
    if (count <= 0) return;

    if (t < count) {
        int i  = base + t;
        int cb = c >> 4;                      // CBW = 16*GCH
        int loc = (c & 15) * GCH + t;
        const float* p = aggP + (size_t)cb * NSB * CBW + loc;
        float a = 0.f;
        #pragma unroll
        for (int r = 0; r < NSB; ++r) a += p[r * CBW];
        float di = dinv[i];
        sh_s[t] = di * (a + x[i] * di);
        sh_b[t] = batch[i];
    }
    __syncthreads();

    const float wa = Wc[t];
    const float wb = bc[t];
    float tsum = 0.f, t2sum = 0.f, gsum = 0.f;
    int gid = sh_b[0];
    int n = 0;
    for (; n + 2 <= count; n += 2) {
        float z0 = fmaf(sh_s[n],     wa, wb);
        float z1 = fmaf(sh_s[n + 1], wa, wb);
        float h0 = gelu_fast(z0);
        float h1 = gelu_fast(z1);
        tsum += h0; t2sum += h0 * h0;
        int b0 = sh_b[n];
        if (b0 != gid) { atomicAdd(&Sgj[gid * HID + t], gsum); gsum = 0.f; gid = b0; }
        gsum += h0;
        tsum += h1; t2sum += h1 * h1;
        int b1 = sh_b[n + 1];
        if (b1 != gid) { atomicAdd(&Sgj[gid * HID + t], gsum); gsum = 0.f; gid = b1; }
        gsum += h1;
    }
    if (n < count) {
        float z0 = fmaf(sh_s[n], wa, wb);
        float h0 = gelu_fast(z0);
        tsum += h0; t2sum += h0 * h0;
        int b0 = sh_b[n];
        if (b0 != gid) { atomicAdd(&Sgj[gid * HID + t], gsum); gsum = 0.f; gid = b0; }
        gsum += h0;
    }
    atomicAdd(&Sgj[gid * HID + t], gsum);
    const int rr = c & (NREP - 1);
    atomicAdd(&Trep [rr * HID + t], tsum);
    atomicAdd(&T2rep[rr * HID + t], t2sum);
}

// ================= tier-2 kernels (round-5 path) =================
__global__ __launch_bounds__(PLACE_THREADS) void k_place(
        const int* __restrict__ src, const int* __restrict__ dst,
        int* __restrict__ binCursor, int* __restrict__ recs, int E) {
    __shared__ int hist[NBINS];
    const int t = threadIdx.x;
    if (t < NBINS) hist[t] = 0;
    __syncthreads();
    const int s0 = blockIdx.x * PLACE_CHUNK;
    const int e0 = min(s0 + PLACE_CHUNK, E);
    for (int i = s0 + t; i < e0; i += PLACE_THREADS)
        atomicAdd(&hist[dst[i] / BINW], 1);
    __syncthreads();
    {
        int b = (t + (int)blockIdx.x * 64) & (NBINS - 1);
        int c = hist[b];
        hist[b] = c ? atomicAdd(&binCursor[b], c) : 0;
    }
    __syncthreads();
    for (int i = s0 + t; i < e0; i += PLACE_THREADS) {
        int d = dst[i];
        int bin = d / BINW;
        int pos = atomicAdd(&hist[bin], 1);
        recs[pos] = ((d - bin * BINW) << 17) | src[i];
    }
}

__global__ __launch_bounds__(256) void k_degdinv(
        const int* __restrict__ recs, const int* __restrict__ binCursor,
        float* __restrict__ dinv, int N) {
    __shared__ int degL[BINW];
    const int b = blockIdx.x;
    const int t = threadIdx.x;
    if (t < BINW) degL[t] = 0;
    __syncthreads();
    const int start = b * BINCAP;
    const int end   = binCursor[b];
    for (int i = start + t; i < end; i += 256)
        atomicAdd(&degL[recs[i] >> 17], 1);
    __syncthreads();
    int node = b * BINW + t;
    if (t < BINW && node < N)
        dinv[node] = rsqrtf((float)degL[t] + 1.0f);
}

__global__ __launch_bounds__(256) void k_aggs_gelu(
        const int* __restrict__ recs, const int* __restrict__ binCursor,
        const float* __restrict__ x, const float* __restrict__ dinv,
        const int* __restrict__ batch,
        const float* __restrict__ Wc, const float* __restrict__ bc,
        float* __restrict__ Sgj, float* __restrict__ Trep, float* __restrict__ T2rep,
        int N) {
    __shared__ float aggL[BINW];
    __shared__ float sh_s[BINW];
    __shared__ int   sh_b[BINW];
    const int b = blockIdx.x;
    const int t = threadIdx.x;
    if (t < BINW) aggL[t] = 0.0f;
    __syncthreads();
    const int start = b * BINCAP;
    const int end   = binCursor[b];
    for (int i = start + t; i < end; i += 256) {
        int rec = recs[i];
        int sN  = rec & 0x1FFFF;
        atomicAdd(&aggL[rec >> 17], x[sN] * dinv[sN]);
    }
    __syncthreads();
    const int node0 = b * BINW;
    const int count = min(BINW, N - node0);
    if (count <= 0) return;
    if (t < count) {
        int node = node0 + t;
        float di = dinv[node];
        sh_s[t] = di * (aggL[t] + x[node] * di);
        sh_b[t] = batch[node];
    }
    __syncthreads();
    const float a  = Wc[t];
    const float bb = bc[t];
    float tsum = 0.f, t2sum = 0.f, gsum = 0.f;
    int gid = sh_b[0];
    for (int n = 0; n < count; ++n) {
        float z = fmaf(sh_s[n], a, bb);
        float h = gelu_fast(z);
        tsum  += h;
        t2sum += h * h;
        int bg = sh_b[n];
        if (bg != gid) { atomicAdd(&Sgj[gid * HID + t], gsum); gsum = 0.f; gid = bg; }
        gsum += h;
    }
    atomicAdd(&Sgj[gid * HID + t], gsum);
    const int r = b & (NREP - 1);
    atomicAdd(&Trep [r * HID + t], tsum);
    atomicAdd(&T2rep[r * HID + t], t2sum);
}

// ================= shared epilogue =================
__global__ __launch_bounds__(HID) void k_pool(
        const float* __restrict__ Sgj, const float* __restrict__ Trep, const float* __restrict__ T2rep,
        const int* __restrict__ cnt, const float* __restrict__ gamma, const float* __restrict__ beta,
        float* __restrict__ pooled, int N) {
    const int j = threadIdx.x;
    const int g = blockIdx.x;
    float Ts = 0.f, T2s = 0.f;
    #pragma unroll
    for (int r = 0; r < NREP; ++r) { Ts += Trep[r * HID + j]; T2s += T2rep[r * HID + j]; }
    float invN = 1.0f / (float)N;
    float mean = Ts * invN;
    float var  = fmaf(-mean, mean, T2s * invN);
    float rinv = rsqrtf(var + BN_EPS);
    float c = (float)max(cnt[g], 1);
    pooled[g * HID + j] = (Sgj[g * HID + j] / c - mean) * rinv * gamma[j] + beta[j];
}

__global__ __launch_bounds__(MLP1) void k_mlp(
        const float* __restrict__ pooled, const float* __restrict__ yfeat,
        const float* __restrict__ W1, const float* __restrict__ b1,
        const float* __restrict__ W2, const float* __restrict__ b2,
        float* __restrict__ out) {
    __shared__ float gv[HID + ADDF];
    __shared__ float hid[MLP1];
    const int g = blockIdx.x;
    const int t = threadIdx.x;
    for (int k = t; k < HID; k += MLP1) gv[k] = pooled[g * HID + k];
    if (t < ADDF) gv[HID + t] = yfeat[g * ADDF + t];
    __syncthreads();
    float acc = b1[t];
    #pragma unroll 8
    for (int k = 0; k < HID + ADDF; ++k)
        acc = fmaf(gv[k], W1[k * MLP1 + t], acc);
    hid[t] = gelu_exact(acc);
    __syncthreads();
    if (t < 2) {
        float o = b2[t];
        for (int k = 0; k < MLP1; ++k)
            o = fmaf(hid[k], W2[k * 2 + t], o);
        out[g * 2 + t] = 1.0f / (1.0f + expf(-o));
    }
}

// ================= tier-3 (global-atomic) kernels =================
__global__ void k_zero(float* p, int n) {
    for (int i = blockIdx.x * blockDim.x + threadIdx.x; i < n; i += gridDim.x * blockDim.x)
        p[i] = 0.0f;
}
__global__ void k_deg_fb(const int* __restrict__ dst, float* __restrict__ deg, int E) {
    int i = blockIdx.x * blockDim.x + threadIdx.x;
    if (i < E) atomicAdd(&deg[dst[i]], 1.0f);
}
__global__ void k_dinv_fb(float* __restrict__ deg, int N) {
    int i = blockIdx.x * blockDim.x + threadIdx.x;
    if (i < N) deg[i] = rsqrtf(deg[i] + 1.0f);
}
__global__ void k_scatter_fb(const int* __restrict__ src, const int* __restrict__ dst,
                             const float* __restrict__ x, const float* __restrict__ dinv,
                             float* __restrict__ agg, int E) {
    int i = blockIdx.x * blockDim.x + threadIdx.x;
    if (i < E) { int s = src[i]; atomicAdd(&agg[dst[i]], x[s] * dinv[s]); }
}
#define CHUNK_FB 64
__global__ __launch_bounds__(HID) void k_gelu_fb(
        const float* __restrict__ x, const float* __restrict__ dinv,
        const float* __restrict__ agg, const int* __restrict__ batch,
        const float* __restrict__ Wc, const float* __restrict__ bc,
        float* __restrict__ Sgj, float* __restrict__ Trep, float* __restrict__ T2rep, int N) {
    __shared__ float sh_s[CHUNK_FB];
    __shared__ int   sh_b[CHUNK_FB];
    const int j = threadIdx.x;
    const int base = blockIdx.x * CHUNK_FB;
    const int count = min(CHUNK_FB, N - base);
    if (j < count) {
        int i = base + j;
        float di = dinv[i];
        sh_s[j] = di * (agg[i] + x[i] * di);
        sh_b[j] = batch[i];
    }
    __syncthreads();
    const float a = Wc[j];
    const float b = bc[j];
    float tsum = 0.f, t2sum = 0.f, gsum = 0.f;
    int gid = sh_b[0];
    for (int n = 0; n < count; ++n) {
        float z = fmaf(sh_s[n], a, b);
        float h = gelu_fast(z);
        tsum += h; t2sum += h * h;
        int bg = sh_b[n];
        if (bg != gid) { atomicAdd(&Sgj[gid * HID + j], gsum); gsum = 0.f; gid = bg; }
        gsum += h;
    }
    atomicAdd(&Sgj[gid * HID + j], gsum);
    const int r = blockIdx.x & (NREP - 1);
    atomicAdd(&Trep [r * HID + j], tsum);
    atomicAdd(&T2rep[r * HID + j], t2sum);
}

extern "C" void kernel_launch(void* const* d_in, const int* in_sizes, int n_in,
                              void* d_out, int out_size, void* d_ws, size_t ws_size,
                              hipStream_t stream) {
    const float* x     = (const float*)d_in[0];
    const int*   edge  = (const int*)  d_in[1];
    const int*   batch = (const int*)  d_in[2];
    const float* yfeat = (const float*)d_in[3];
    const float* Wc    = (const float*)d_in[4];
    const float* bc    = (const float*)d_in[5];
    const float* gamma = (const float*)d_in[6];
    const float* beta  = (const float*)d_in[7];
    const float* W1    = (const float*)d_in[8];
    const float* b1    = (const float*)d_in[9];
    const float* W2    = (const float*)d_in[10];
    const float* b2    = (const float*)d_in[11];
    float* out = (float*)d_out;

    const int N = in_sizes[0];          // 100000
    const int E = in_sizes[1] / 2;      // 1600000
    const int G = in_sizes[3] / ADDF;   // 256

    const int* srcIdx = edge;
    const int* dstIdx = edge + E;

    // ---- workspace layout ----
    float* ws     = (float*)d_ws;
    float* Sgj    = ws;                              // [G*HID]    zeroed
    float* Trep   = Sgj + (size_t)G * HID;           // [NREP*HID] zeroed
    float* T2rep  = Trep + NREP * HID;               // [NREP*HID] zeroed
    int*   cnt    = (int*)(T2rep + NREP * HID);      // [G]
    int*   binCur = cnt + G;                         // [1024] (both tiers)
    float* dinv   = (float*)(binCur + 1024);         // [100352]
    float* pooled = dinv + 100352;                   // [G*HID]
    int*   partP  = (int*)(pooled + (size_t)G * HID); // tier1: [NCB*NSB*CBW]; tier2: recs start here
    int*   recs1  = partP + (size_t)NCB * NSB * CBW;  // tier1: [NCB*CBCAP]
    int*   recs2  = partP;                            // tier2: [NBINS*BINCAP]

    const size_t headF = (size_t)G * HID + 2 * NREP * HID + (G + 1024 + 100352 + (size_t)G * HID);
    const size_t needT1 = (headF + (size_t)NCB * NSB * CBW + (size_t)NCB * CBCAP) * 4;
    const size_t needT2 = (headF + (size_t)NBINS * BINCAP) * 4;
    const int zeroCount = G * HID + 2 * NREP * HID;
    const int initBlocks = (zeroCount + 255) / 256 + 1;

    if (ws_size >= needT1 && N < (1 << 17) && N <= NCB * CBW) {
        // ---- tier 1: two-level binned path ----
        k_init<<<initBlocks, 256, 0, stream>>>(Sgj, zeroCount, binCur, NCB, CBCAP, batch, cnt, N, G);
        k_place1<<<(E + PC1 - 1) / PC1, P1T, 0, stream>>>(srcIdx, dstIdx, binCur, recs1, E);
        k_deg2<<<NCB * NSB, 256, 0, stream>>>(recs1, binCur, partP);
        k_dinvk<<<(N + 255) / 256, 256, 0, stream>>>(partP, dinv, N);
        k_agg2<<<NCB * NSB, 256, 0, stream>>>(recs1, binCur, x, dinv, (float*)partP);
        k_gelu<<<(N + GCH - 1) / GCH, HID, 0, stream>>>(x, dinv, (const float*)partP, batch, Wc, bc, Sgj, Trep, T2rep, N);
    } else if (ws_size >= needT2 && N < (1 << 17)) {
        // ---- tier 2: one-level binned path ----
        k_init<<<initBlocks, 256, 0, stream>>>(Sgj, zeroCount, binCur, NBINS, BINCAP, batch, cnt, N, G);
        k_place<<<(E + PLACE_CHUNK - 1) / PLACE_CHUNK, PLACE_THREADS, 0, stream>>>(srcIdx, dstIdx, binCur, recs2, E);
        k_degdinv<<<NBINS, 256, 0, stream>>>(recs2, binCur, dinv, N);
        k_aggs_gelu<<<NBINS, 256, 0, stream>>>(recs2, binCur, x, dinv, batch, Wc, bc, Sgj, Trep, T2rep, N);
    } else {
        // ---- tier 3: global-atomic path ----
        float* deg = dinv;
        float* agg = (float*)partP;
        k_init<<<initBlocks, 256, 0, stream>>>(Sgj, zeroCount, binCur, 0, 0, batch, cnt, N, G);
        k_zero<<<512, 256, 0, stream>>>(deg, N);
        k_zero<<<512, 256, 0, stream>>>(agg, N);
        k_deg_fb<<<(E + 255) / 256, 256, 0, stream>>>(dstIdx, deg, E);
        k_dinv_fb<<<(N + 255) / 256, 256, 0, stream>>>(deg, N);
        k_scatter_fb<<<(E + 255) / 256, 256, 0, stream>>>(srcIdx, dstIdx, x, deg, agg, E);
        k_gelu_fb<<<(N + CHUNK_FB - 1) / CHUNK_FB, HID, 0, stream>>>(x, deg, agg, batch, Wc, bc, Sgj, Trep, T2rep, N);
    }

    k_pool<<<G, HID, 0, stream>>>(Sgj, Trep, T2rep, cnt, gamma, beta, pooled, N);
    k_mlp<<<G, MLP1, 0, stream>>>(pooled, yfeat, W1, b1, W2, b2, out);
}

// Round 7
// 86.403 us; speedup vs baseline: 4.3516x; 1.0869x over previous
//
#include <hip/hip_runtime.h>
#include <hip/hip_bf16.h>

#define HID 256
#define ADDF 7
#define MLP1 128
#define BN_EPS 1e-5f
#define NREP 8

// ---- binning: 512 bins x 196 nodes ----
#define NB 512
#define BW 196               // NB*BW = 100352 >= N
#define BCAP 4096            // mean 3136 edges/bin, +17 sigma
#define PC 4096              // edges per place block
#define PT 256               // place threads
#define NW 4                 // waves per place block

// tanh-form gelu: z*u/(u+1), u = exp(z*(2c0 + 2c0c1 z^2))
__device__ __forceinline__ float gelu_fast(float z) {
    float z2 = z * z;
    float y2 = z * fmaf(0.07135481627f, z2, 1.59576912161f);
    float u  = __expf(fminf(y2, 80.0f));
    return z * u * __builtin_amdgcn_rcpf(u + 1.0f);
}

// ---------------- init: zero accumulators, cursors, graph counts ----------------
__global__ void k_init(float* zp, int nz, int* binCur,
                       const int* __restrict__ batch, int* __restrict__ cnt, int N, int G) {
    const int nzBlocks = (nz + 255) / 256;
    if ((int)blockIdx.x < nzBlocks) {
        int i = blockIdx.x * 256 + threadIdx.x;
        if (i < nz) zp[i] = 0.0f;
    } else {
        const int t = threadIdx.x;
        for (int b = t; b < NB; b += 256) binCur[b] = b * BCAP;
        if (t < G) {
            int lo = 0, hi = N;
            while (lo < hi) { int mid = (lo + hi) >> 1; if (batch[mid] < t) lo = mid + 1; else hi = mid; }
            int start = lo;
            lo = 0; hi = N;
            while (lo < hi) { int mid = (lo + hi) >> 1; if (batch[mid] < t + 1) lo = mid + 1; else hi = mid; }
            cnt[t] = lo - start;
        }
    }
}

// ---------------- place edges into dst-range bins (per-wave cursors) ----------------
__global__ __launch_bounds__(PT) void k_place(
        const int* __restrict__ src, const int* __restrict__ dst,
        int* __restrict__ binCur, int* __restrict__ recs, int E) {
    __shared__ int hist[NW][NB];
    const int t = threadIdx.x;
    const int w = t >> 6;
    for (int k = t; k < NW * NB; k += PT) (&hist[0][0])[k] = 0;
    __syncthreads();

    const int s0 = blockIdx.x * PC;
    const int e0 = min(s0 + PC, E);
    const bool vec = ((E & 3) == 0);
    const int n4 = vec ? ((e0 - s0) >> 2) : 0;
    const int4* dst4 = (const int4*)(dst + s0);
    const int4* src4 = (const int4*)(src + s0);

    // phase 1: histogram
    for (int q = t; q < n4; q += PT) {
        int4 d = dst4[q];
        atomicAdd(&hist[w][d.x / BW], 1);
        atomicAdd(&hist[w][d.y / BW], 1);
        atomicAdd(&hist[w][d.z / BW], 1);
        atomicAdd(&hist[w][d.w / BW], 1);
    }
    for (int i = s0 + (n4 << 2) + t; i < e0; i += PT)
        atomicAdd(&hist[w][dst[i] / BW], 1);
    __syncthreads();

    // phase 2: reserve per-bin space, distribute per-wave bases (staggered)
    for (int bb = t; bb < NB; bb += PT) {
        int b = (bb + ((int)blockIdx.x << 4)) & (NB - 1);
        int c0 = hist[0][b], c1 = hist[1][b], c2 = hist[2][b], c3 = hist[3][b];
        int tot = c0 + c1 + c2 + c3;
        int base = tot ? atomicAdd(&binCur[b], tot) : 0;
        hist[0][b] = base;
        hist[1][b] = base + c0;
        hist[2][b] = base + c0 + c1;
        hist[3][b] = base + c0 + c1 + c2;
    }
    __syncthreads();

    // phase 3: store records
    for (int q = t; q < n4; q += PT) {
        int4 d = dst4[q];
        int4 s = src4[q];
        int bin, pos;
        bin = d.x / BW; pos = atomicAdd(&hist[w][bin], 1); recs[pos] = ((d.x - bin * BW) << 17) | s.x;
        bin = d.y / BW; pos = atomicAdd(&hist[w][bin], 1); recs[pos] = ((d.y - bin * BW) << 17) | s.y;
        bin = d.z / BW; pos = atomicAdd(&hist[w][bin], 1); recs[pos] = ((d.z - bin * BW) << 17) | s.z;
        bin = d.w / BW; pos = atomicAdd(&hist[w][bin], 1); recs[pos] = ((d.w - bin * BW) << 17) | s.w;
    }
    for (int i = s0 + (n4 << 2) + t; i < e0; i += PT) {
        int d = dst[i];
        int bin = d / BW;
        int pos = atomicAdd(&hist[w][bin], 1);
        recs[pos] = ((d - bin * BW) << 17) | src[i];
    }
}

// ---------------- per-bin degree -> dinv, v = x*dinv ----------------
__global__ __launch_bounds__(256) void k_degv(
        const int* __restrict__ recs, const int* __restrict__ binCur,
        const float* __restrict__ x, float* __restrict__ dinv, float* __restrict__ v, int N) {
    __shared__ int degL[BW];
    const int b = blockIdx.x;
    const int t = threadIdx.x;
    if (t < BW) degL[t] = 0;
    __syncthreads();

    const int start = b * BCAP;
    const int end   = binCur[b];
    const int n4 = (end - start) >> 2;
    const int4* r4 = (const int4*)(recs + start);
    for (int q = t; q < n4; q += 256) {
        int4 r = r4[q];
        atomicAdd(&degL[r.x >> 17], 1);
        atomicAdd(&degL[r.y >> 17], 1);
        atomicAdd(&degL[r.z >> 17], 1);
        atomicAdd(&degL[r.w >> 17], 1);
    }
    for (int i = start + (n4 << 2) + t; i < end; i += 256)
        atomicAdd(&degL[recs[i] >> 17], 1);
    __syncthreads();

    int node = b * BW + t;
    if (t < BW && node < N) {
        float di = rsqrtf((float)degL[t] + 1.0f);   // +1 self-loop
        dinv[node] = di;
        v[node]    = di * x[node];
    }
}

// ---------------- fused: per-bin agg -> s -> gelu accumulate ----------------
__global__ __launch_bounds__(HID) void k_agg_gelu(
        const int* __restrict__ recs, const int* __restrict__ binCur,
        const float* __restrict__ v, const float* __restrict__ dinv,
        const int* __restrict__ batch,
        const float* __restrict__ Wc, const float* __restrict__ bc,
        float* __restrict__ Sgj, float* __restrict__ Trep, float* __restrict__ T2rep, int N) {
    __shared__ float aggL[BW];
    __shared__ float sh_s[BW];
    __shared__ int   sh_b[BW];
    const int b = blockIdx.x;
    const int t = threadIdx.x;
    if (t < BW) aggL[t] = 0.0f;
    __syncthreads();

    const int start = b * BCAP;
    const int end   = binCur[b];
    const int n4 = (end - start) >> 2;
    const int4* r4 = (const int4*)(recs + start);
    for (int q = t; q < n4; q += 256) {
        int4 r = r4[q];
        atomicAdd(&aggL[r.x >> 17], v[r.x & 0x1FFFF]);
        atomicAdd(&aggL[r.y >> 17], v[r.y & 0x1FFFF]);
        atomicAdd(&aggL[r.z >> 17], v[r.z & 0x1FFFF]);
        atomicAdd(&aggL[r.w >> 17], v[r.w & 0x1FFFF]);
    }
    for (int i = start + (n4 << 2) + t; i < end; i += 256) {
        int rec = recs[i];
        atomicAdd(&aggL[rec >> 17], v[rec & 0x1FFFF]);
    }
    __syncthreads();

    const int node0 = b * BW;
    const int count = min(BW, N - node0);
    if (count <= 0) return;

    if (t < count) {
        int node = node0 + t;
        sh_s[t] = dinv[node] * (aggL[t] + v[node]);   // s = dinv*(agg + x*dinv)
        sh_b[t] = batch[node];
    }
    __syncthreads();

    const float wa = Wc[t];
    const float wb = bc[t];
    float tsum = 0.f, t2sum = 0.f, gsum = 0.f;
    int gid = sh_b[0];
    int n = 0;
    for (; n + 2 <= count; n += 2) {
        float h0 = gelu_fast(fmaf(sh_s[n],     wa, wb));
        float h1 = gelu_fast(fmaf(sh_s[n + 1], wa, wb));
        int b0 = sh_b[n], b1v = sh_b[n + 1];
        tsum += h0 + h1; t2sum += fmaf(h0, h0, h1 * h1);
        if (b0 != gid)  { atomicAdd(&Sgj[gid * HID + t], gsum); gsum = 0.f; gid = b0; }
        gsum += h0;
        if (b1v != gid) { atomicAdd(&Sgj[gid * HID + t], gsum); gsum = 0.f; gid = b1v; }
        gsum += h1;
    }
    if (n < count) {
        float h0 = gelu_fast(fmaf(sh_s[n], wa, wb));
        tsum += h0; t2sum += h0 * h0;
        int b0 = sh_b[n];
        if (b0 != gid) { atomicAdd(&Sgj[gid * HID + t], gsum); gsum = 0.f; gid = b0; }
        gsum += h0;
    }
    atomicAdd(&Sgj[gid * HID + t], gsum);
    const int r = b & (NREP - 1);
    atomicAdd(&Trep [r * HID + t], tsum);
    atomicAdd(&T2rep[r * HID + t], t2sum);
}

// ---------------- fused pool + BN + MLP ----------------
__global__ __launch_bounds__(HID) void k_pool_mlp(
        const float* __restrict__ Sgj, const float* __restrict__ Trep, const float* __restrict__ T2rep,
        const int* __restrict__ cnt, const float* __restrict__ gamma, const float* __restrict__ beta,
        const float* __restrict__ yfeat,
        const float* __restrict__ W1, const float* __restrict__ b1,
        const float* __restrict__ W2, const float* __restrict__ b2,
        float* __restrict__ out, int N) {
    __shared__ float gv[HID + ADDF];
    __shared__ float hid[MLP1];
    const int g = blockIdx.x;
    const int t = threadIdx.x;

    float Ts = 0.f, T2s = 0.f;
    #pragma unroll
    for (int r = 0; r < NREP; ++r) { Ts += Trep[r * HID + t]; T2s += T2rep[r * HID + t]; }
    float invN = 1.0f / (float)N;
    float mean = Ts * invN;
    float var  = fmaf(-mean, mean, T2s * invN);
    float rinv = rsqrtf(var + BN_EPS);
    float c = (float)max(cnt[g], 1);
    gv[t] = (Sgj[g * HID + t] / c - mean) * rinv * gamma[t] + beta[t];
    if (t < ADDF) gv[HID + t] = yfeat[g * ADDF + t];
    __syncthreads();

    if (t < MLP1) {
        float acc = b1[t];
        #pragma unroll 8
        for (int k = 0; k < HID + ADDF; ++k)
            acc = fmaf(gv[k], W1[k * MLP1 + t], acc);
        hid[t] = gelu_fast(acc);
    }
    __syncthreads();

    if (t < 2) {
        float o = b2[t];
        for (int k = 0; k < MLP1; ++k)
            o = fmaf(hid[k], W2[k * 2 + t], o);
        out[g * 2 + t] = 1.0f / (1.0f + expf(-o));
    }
}

// ================= fallback (global-atomic) kernels =================
__global__ void k_zero(float* p, int n) {
    for (int i = blockIdx.x * blockDim.x + threadIdx.x; i < n; i += gridDim.x * blockDim.x)
        p[i] = 0.0f;
}
__global__ void k_deg_fb(const int* __restrict__ dst, float* __restrict__ deg, int E) {
    int i = blockIdx.x * blockDim.x + threadIdx.x;
    if (i < E) atomicAdd(&deg[dst[i]], 1.0f);
}
__global__ void k_dinv_fb(float* __restrict__ deg, const float* __restrict__ x,
                          float* __restrict__ v, int N) {
    int i = blockIdx.x * blockDim.x + threadIdx.x;
    if (i < N) { float di = rsqrtf(deg[i] + 1.0f); deg[i] = di; v[i] = di * x[i]; }
}
__global__ void k_scatter_fb(const int* __restrict__ src, const int* __restrict__ dst,
                             const float* __restrict__ v, float* __restrict__ agg, int E) {
    int i = blockIdx.x * blockDim.x + threadIdx.x;
    if (i < E) atomicAdd(&agg[dst[i]], v[src[i]]);
}
#define CHUNK_FB 64
__global__ __launch_bounds__(HID) void k_gelu_fb(
        const float* __restrict__ v, const float* __restrict__ dinv,
        const float* __restrict__ agg, const int* __restrict__ batch,
        const float* __restrict__ Wc, const float* __restrict__ bc,
        float* __restrict__ Sgj, float* __restrict__ Trep, float* __restrict__ T2rep, int N) {
    __shared__ float sh_s[CHUNK_FB];
    __shared__ int   sh_b[CHUNK_FB];
    const int j = threadIdx.x;
    const int base = blockIdx.x * CHUNK_FB;
    const int count = min(CHUNK_FB, N - base);
    if (j < count) {
        int i = base + j;
        sh_s[j] = dinv[i] * (agg[i] + v[i]);
        sh_b[j] = batch[i];
    }
    __syncthreads();
    const float a = Wc[j];
    const float b = bc[j];
    float tsum = 0.f, t2sum = 0.f, gsum = 0.f;
    int gid = sh_b[0];
    for (int n = 0; n < count; ++n) {
        float h = gelu_fast(fmaf(sh_s[n], a, b));
        tsum += h; t2sum += h * h;
        int bg = sh_b[n];
        if (bg != gid) { atomicAdd(&Sgj[gid * HID + j], gsum); gsum = 0.f; gid = bg; }
        gsum += h;
    }
    atomicAdd(&Sgj[gid * HID + j], gsum);
    const int r = blockIdx.x & (NREP - 1);
    atomicAdd(&Trep [r * HID + j], tsum);
    atomicAdd(&T2rep[r * HID + j], t2sum);
}

extern "C" void kernel_launch(void* const* d_in, const int* in_sizes, int n_in,
                              void* d_out, int out_size, void* d_ws, size_t ws_size,
                              hipStream_t stream) {
    const float* x     = (const float*)d_in[0];
    const int*   edge  = (const int*)  d_in[1];
    const int*   batch = (const int*)  d_in[2];
    const float* yfeat = (const float*)d_in[3];
    const float* Wc    = (const float*)d_in[4];
    const float* bc    = (const float*)d_in[5];
    const float* gamma = (const float*)d_in[6];
    const float* beta  = (const float*)d_in[7];
    const float* W1    = (const float*)d_in[8];
    const float* b1    = (const float*)d_in[9];
    const float* W2    = (const float*)d_in[10];
    const float* b2    = (const float*)d_in[11];
    float* out = (float*)d_out;

    const int N = in_sizes[0];          // 100000
    const int E = in_sizes[1] / 2;      // 1600000
    const int G = in_sizes[3] / ADDF;   // 256

    const int* srcIdx = edge;
    const int* dstIdx = edge + E;

    // ---- workspace layout ----
    float* ws     = (float*)d_ws;
    float* Sgj    = ws;                              // [G*HID]    zeroed
    float* Trep   = Sgj + (size_t)G * HID;           // [NREP*HID] zeroed
    float* T2rep  = Trep + NREP * HID;               // [NREP*HID] zeroed
    int*   cnt    = (int*)(T2rep + NREP * HID);      // [G]
    int*   binCur = cnt + G;                         // [NB]
    float* dinv   = (float*)(binCur + NB);           // [NB*BW]
    float* v      = dinv + (size_t)NB * BW;          // [NB*BW]
    int*   recs   = (int*)(v + (size_t)NB * BW);     // [NB*BCAP]

    const size_t headF  = (size_t)G * HID + 2 * NREP * HID + G + NB;
    const size_t needT1 = (headF + 2 * (size_t)NB * BW + (size_t)NB * BCAP) * 4;
    const int zeroCount = G * HID + 2 * NREP * HID;
    const int initBlocks = (zeroCount + 255) / 256 + 1;

    if (ws_size >= needT1 && N <= NB * BW) {
        // ---- binned path: 5 launches ----
        k_init<<<initBlocks, 256, 0, stream>>>(Sgj, zeroCount, binCur, batch, cnt, N, G);
        k_place<<<(E + PC - 1) / PC, PT, 0, stream>>>(srcIdx, dstIdx, binCur, recs, E);
        k_degv<<<NB, 256, 0, stream>>>(recs, binCur, x, dinv, v, N);
        k_agg_gelu<<<NB, HID, 0, stream>>>(recs, binCur, v, dinv, batch, Wc, bc, Sgj, Trep, T2rep, N);
    } else {
        // ---- fallback: global-atomic path (generic N) ----
        float* degA = (float*)(binCur + NB);         // [N]
        float* vA   = degA + N;                      // [N]
        float* aggA = vA + N;                        // [N]
        k_init<<<initBlocks, 256, 0, stream>>>(Sgj, zeroCount, binCur, batch, cnt, N, G);
        k_zero<<<512, 256, 0, stream>>>(degA, N);
        k_zero<<<512, 256, 0, stream>>>(aggA, N);
        k_deg_fb<<<(E + 255) / 256, 256, 0, stream>>>(dstIdx, degA, E);
        k_dinv_fb<<<(N + 255) / 256, 256, 0, stream>>>(degA, x, vA, N);
        k_scatter_fb<<<(E + 255) / 256, 256, 0, stream>>>(srcIdx, dstIdx, vA, aggA, E);
        k_gelu_fb<<<(N + CHUNK_FB - 1) / CHUNK_FB, HID, 0, stream>>>(vA, degA, aggA, batch, Wc, bc, Sgj, Trep, T2rep, N);
    }

    k_pool_mlp<<<G, HID, 0, stream>>>(Sgj, Trep, T2rep, cnt, gamma, beta, yfeat, W1, b1, W2, b2, out, N);
}